// Round 8
// baseline (4211.477 us; speedup 1.0000x reference)
//
#include <hip/hip_runtime.h>
#include <hip/hip_bf16.h>

// ---------------- sizes ----------------
#define T_STEPS 256
#define MDIM 1024
#define MROWS 512
#define NBLK 256
#define NTHR 512

// ws float offsets
#define OFF_WGB     0u                      // bf16 [1024][4096] interleaved gates (2M floats)
#define OFF_WATT    2097152u                // fp32 [1024][1024] W_attnh top, transposed
#define OFF_HPRE    3145728u                // fp32 [512][1024]
#define OFF_XIOU    3670016u                // fp32 [256][3072]
#define OFF_XF      4456448u                // fp32 [256][1024]
#define OFF_G       4718592u                // bf16 [512][4096]  G = H @ Wg (1M floats)
#define OFF_HT      5767168u                // fp32 [1024][512]  H transposed
#define OFF_HCOL    6291456u                // fp32 [1024]
#define OFF_HCOLW   6292480u                // fp32 [4096]  Hcol @ Wg
#define OFF_HNEW    6296576u                // fp32 [1024]   (zeroed)
#define OFF_E       6297600u                // fp32 [512]    (zeroed)
#define OFF_BAR     6298112u                // 4112 u32      (zeroed)
#define OFF_ATTV    6302224u                // fp32 [1024]

__device__ inline float fast_tanh(float v) {
    float x = fminf(fmaxf(v, -15.f), 15.f);
    float z = __expf(2.f * x);
    return (z - 1.f) / (z + 1.f);
}
__device__ inline float sigm(float v) { return 1.f / (1.f + __expf(-v)); }

__device__ inline float wave_red(float v) {
#pragma unroll
    for (int s = 32; s > 0; s >>= 1) v += __shfl_down(v, s, 64);
    return v;
}

__device__ __host__ inline unsigned short f2b(float f) {
    __hip_bfloat16 h = __float2bfloat16(f);
    return *(unsigned short*)&h;
}
__device__ inline float b2f(unsigned short u) {
    union { unsigned i; float f; } v; v.i = ((unsigned)u) << 16; return v.f;
}

// device-scope relaxed atomics: LLC-direct, no L2 invalidate anywhere
__device__ inline float gload(const float* p) {
    return __hip_atomic_load(p, __ATOMIC_RELAXED, __HIP_MEMORY_SCOPE_AGENT);
}
__device__ inline void gstore(float* p, float v) {
    __hip_atomic_store(p, v, __ATOMIC_RELAXED, __HIP_MEMORY_SCOPE_AGENT);
}

// Two-level RMW barrier, all-RELAXED, last-arriver detection (round-8 change).
// vs round-7 root-poller: removes BOTH polling stages from the detection path.
// thread 0 per block: fetch_add on 1-of-8 padded sub-counters (32 blocks each;
// arrival detected synchronously from the RMW return — no poll); 32nd arriver
// bumps root; the 8th root RMW IS the broadcast (waiters poll root >= 8*ep,
// no separate flag-store hop). Visibility (twice-validated): data stores are
// agent-scope relaxed; s_waitcnt(0) ack => LLC-visible before arrival RMW.
__device__ inline void gsync(unsigned* bar, unsigned ep) {
    __syncthreads();
    __builtin_amdgcn_s_waitcnt(0);
    if (threadIdx.x == 0) {
        unsigned o = __hip_atomic_fetch_add(&bar[16 + (blockIdx.x & 7) * 16], 1u,
                                            __ATOMIC_RELAXED, __HIP_MEMORY_SCOPE_AGENT);
        if (o == ep * 32u - 1u)
            __hip_atomic_fetch_add(&bar[0], 1u, __ATOMIC_RELAXED,
                                   __HIP_MEMORY_SCOPE_AGENT);
        while (__hip_atomic_load(&bar[0], __ATOMIC_RELAXED,
                                 __HIP_MEMORY_SCOPE_AGENT) < ep * 8u)
            __builtin_amdgcn_s_sleep(1);
    }
    __asm__ volatile("" ::: "memory");
    __syncthreads();
}

// -------- precompute kernels --------

// Wgb[k][4g+{0,1,2,3}] = bf16{W_iouh[k][g], W_iouh[k][m+g], W_iouh[k][2m+g], W_fh[k][g]}
__global__ void build_wg(const float* __restrict__ Wiouh, const float* __restrict__ Wfh,
                         unsigned short* __restrict__ Wgb) {
    int k = blockIdx.y;
    int g = blockIdx.x * 256 + threadIdx.x;
    unsigned a = f2b(Wiouh[k * 3072 + g]);
    unsigned b = f2b(Wiouh[k * 3072 + 1024 + g]);
    unsigned c = f2b(Wiouh[k * 3072 + 2048 + g]);
    unsigned d = f2b(Wfh[k * 1024 + g]);
    uint2 p; p.x = a | (b << 16); p.y = c | (d << 16);
    *(uint2*)(Wgb + (size_t)k * 4096 + 4 * g) = p;
}

// dst[c*R + r] = src[r*C + c]
__global__ void transpose_g(const float* __restrict__ src, float* __restrict__ dst,
                            int R, int C) {
    __shared__ float tile[32][33];
    int c = blockIdx.x * 32 + threadIdx.x;
    int r0 = blockIdx.y * 32;
    for (int i = threadIdx.y; i < 32; i += 8)
        tile[i][threadIdx.x] = src[(size_t)(r0 + i) * C + c];
    __syncthreads();
    int r = r0 + threadIdx.x;
    int c0 = blockIdx.x * 32;
    for (int i = threadIdx.y; i < 32; i += 8)
        dst[(size_t)(c0 + i) * R + r] = tile[threadIdx.x][i];
}

// C[M,N] = A[M,K] @ B[K,N] + b1 + b2
__global__ __launch_bounds__(256) void gemm_bias(const float* __restrict__ A,
                                                 const float* __restrict__ B,
                                                 const float* __restrict__ b1,
                                                 const float* __restrict__ b2,
                                                 float* __restrict__ C,
                                                 int M, int N, int K) {
    __shared__ float As[16][68];
    __shared__ float Bs[16][68];
    int t = threadIdx.x;
    int m0 = blockIdx.y * 64, n0 = blockIdx.x * 64;
    int tx = t & 15, ty = t >> 4;
    float acc[4][4] = {};
    for (int kk = 0; kk < K; kk += 16) {
        {
            int m = t >> 2, k4 = (t & 3) * 4;
            const float4 a4 = *(const float4*)(A + (size_t)(m0 + m) * K + kk + k4);
            As[k4 + 0][m] = a4.x; As[k4 + 1][m] = a4.y;
            As[k4 + 2][m] = a4.z; As[k4 + 3][m] = a4.w;
            int kb = t >> 4, n = (t & 15) * 4;
            const float4 b4 = *(const float4*)(B + (size_t)(kk + kb) * N + n0 + n);
            *(float4*)&Bs[kb][n] = b4;
        }
        __syncthreads();
#pragma unroll
        for (int k = 0; k < 16; k++) {
            float a[4], b[4];
            *(float4*)a = *(const float4*)&As[k][ty * 4];
            *(float4*)b = *(const float4*)&Bs[k][tx * 4];
#pragma unroll
            for (int i = 0; i < 4; i++)
#pragma unroll
                for (int j = 0; j < 4; j++)
                    acc[i][j] = fmaf(a[i], b[j], acc[i][j]);
        }
        __syncthreads();
    }
#pragma unroll
    for (int i = 0; i < 4; i++) {
        int m = m0 + ty * 4 + i;
#pragma unroll
        for (int j = 0; j < 4; j++) {
            int n = n0 + tx * 4 + j;
            float v = acc[i][j];
            if (b1) v += b1[n];
            if (b2) v += b2[n];
            C[(size_t)m * N + n] = v;
        }
    }
}

// G-gemm: Gb[m][4*(n%1024) + n/1024 + cofs] = bf16( (A@B)[m][n] )
__global__ __launch_bounds__(256) void gemm_gi(const float* __restrict__ A,
                                               const float* __restrict__ B,
                                               unsigned short* __restrict__ Gb,
                                               int M, int N, int K, int cofs) {
    __shared__ float As[16][68];
    __shared__ float Bs[16][68];
    int t = threadIdx.x;
    int m0 = blockIdx.y * 64, n0 = blockIdx.x * 64;
    int tx = t & 15, ty = t >> 4;
    float acc[4][4] = {};
    for (int kk = 0; kk < K; kk += 16) {
        {
            int m = t >> 2, k4 = (t & 3) * 4;
            const float4 a4 = *(const float4*)(A + (size_t)(m0 + m) * K + kk + k4);
            As[k4 + 0][m] = a4.x; As[k4 + 1][m] = a4.y;
            As[k4 + 2][m] = a4.z; As[k4 + 3][m] = a4.w;
            int kb = t >> 4, n = (t & 15) * 4;
            const float4 b4 = *(const float4*)(B + (size_t)(kk + kb) * N + n0 + n);
            *(float4*)&Bs[kb][n] = b4;
        }
        __syncthreads();
#pragma unroll
        for (int k = 0; k < 16; k++) {
            float a[4], b[4];
            *(float4*)a = *(const float4*)&As[k][ty * 4];
            *(float4*)b = *(const float4*)&Bs[k][tx * 4];
#pragma unroll
            for (int i = 0; i < 4; i++)
#pragma unroll
                for (int j = 0; j < 4; j++)
                    acc[i][j] = fmaf(a[i], b[j], acc[i][j]);
        }
        __syncthreads();
    }
#pragma unroll
    for (int i = 0; i < 4; i++) {
        int m = m0 + ty * 4 + i;
#pragma unroll
        for (int j = 0; j < 4; j++) {
            int n = n0 + tx * 4 + j;
            int cp = 4 * (n & 1023) + (n >> 10) + cofs;
            Gb[(size_t)m * 4096 + cp] = f2b(acc[i][j]);
        }
    }
}

__global__ void colsum_k(const float* __restrict__ H, float* __restrict__ out) {
    int k = blockIdx.x * 256 + threadIdx.x;
    float s = 0.f;
#pragma unroll 8
    for (int r = 0; r < MROWS; r++) s += H[(size_t)r * MDIM + k];
    out[k] = s;
}

// HcolW[j] = sum_k Hcol[k] * Wgb[k][j]
__global__ void hcolw_k(const float* __restrict__ Hcol,
                        const unsigned short* __restrict__ Wgb,
                        float* __restrict__ HcolW) {
    int j = blockIdx.x * 256 + threadIdx.x;
    float acc = 0.f;
#pragma unroll 8
    for (int k = 0; k < 1024; k++)
        acc = fmaf(Hcol[k], b2f(Wgb[(size_t)k * 4096 + j]), acc);
    HcolW[j] = acc;
}

// -------- persistent recurrent kernel --------
__global__ __launch_bounds__(NTHR) void recurrent(
    const unsigned short* __restrict__ Wgb, const float* __restrict__ WatT,
    const float* __restrict__ Hpre, const float* __restrict__ HT,
    const float* __restrict__ Hcol, const float* __restrict__ HcolW,
    const unsigned short* __restrict__ Gb, const float* __restrict__ X_iou,
    const float* __restrict__ X_f, const float* __restrict__ Wa,
    float* h_new, float* att_v, float* e, unsigned* bar, float* out) {

    const int b = blockIdx.x, t = threadIdx.x;
    const int x = b & 7, y = b >> 3;          // XCD-contiguous slices
    const int g_col = x * 128 + y * 4;        // block's 4 output columns
    const int j0 = x * 512 + y * 16;          // block's 16 interleaved gate cols
    unsigned ep = 0;
    float creg = 0.f;                          // cell state (threads t<4)
    __shared__ float smem[2624];
    float* hs   = smem;          // 1056 padded h_new(st-1)
    float* le   = smem + 1056;   // 512 e(st-1)
    float* red  = smem + 1568;   // [32][16] h_new-dot partials
    float* red2 = smem + 2080;   // [32][16] G-corr partials
    float* sred = smem + 2592;   // 8  (S partials)
    float* sred2= smem + 2600;   // 8  (P partials)
    float* dotb = smem + 2608;   // 16

    for (int st = 0; st < T_STEPS; st++) {
        // ---- Phase A: gates + h_new + out[st-1] ----
        {
            float evv = gload(e + t);
            le[t] = evv;
            float hv0 = gload(h_new + t), hv1 = gload(h_new + t + 512);
            hs[t + (t >> 5)] = hv0;
            { int k2 = t + 512; hs[k2 + (k2 >> 5)] = hv1; }
            float sv = wave_red(evv);
            if ((t & 63) == 0) sred[t >> 6] = sv;
            __syncthreads();

            const int jt = t & 15, kq = t >> 4;
            // h_new-dot over k
            const unsigned short* wp = Wgb + (size_t)(kq * 32) * 4096 + j0 + jt;
            float acc = 0.f;
#pragma unroll 8
            for (int i = 0; i < 32; i++) {
                int k = kq * 32 + i;
                acc = fmaf(hs[k + (k >> 5)], b2f(wp[(size_t)i * 4096]), acc);
            }
            red[kq * 16 + jt] = acc;
            // G-correction over r
            const unsigned short* gp = Gb + (size_t)(kq * 16) * 4096 + j0 + jt;
            float acc2 = 0.f;
#pragma unroll 8
            for (int i = 0; i < 16; i++)
                acc2 = fmaf(le[kq * 16 + i], b2f(gp[(size_t)i * 4096]), acc2);
            red2[kq * 16 + jt] = acc2;
            // P for block's 4 out-cols
            {
                const int kt = t >> 7, rr = t & 127;
                const float* htp = HT + (size_t)(g_col + kt) * 512;
                float pp = 0.f;
#pragma unroll
                for (int i = 0; i < 4; i++) {
                    int r = rr + 128 * i;
                    pp = fmaf(le[r], htp[r], pp);
                }
                pp = wave_red(pp);
                if ((t & 63) == 0) sred2[t >> 6] = pp;
            }
            __syncthreads();
            if (t < 16) {
                float s1 = 0.f, s2 = 0.f;
#pragma unroll
                for (int q = 0; q < 32; q++) { s1 += red[q * 16 + t]; s2 += red2[q * 16 + t]; }
                float S = sred[0] + sred[1] + sred[2] + sred[3]
                        + sred[4] + sred[5] + sred[6] + sred[7];
                float invS = (st == 0) ? 0.f : 1.f / S;
                float hw = (st == 0) ? 0.f : HcolW[j0 + t];
                dotb[t] = s1 + hw - invS * s2;
            }
            __syncthreads();
            if (t < 4) {
                int g = g_col + t;
                float S = sred[0] + sred[1] + sred[2] + sred[3]
                        + sred[4] + sred[5] + sred[6] + sred[7];
                if (st > 0) {
                    float P = sred2[t * 2] + sred2[t * 2 + 1];
                    out[(size_t)(st - 1) * 1024 + g] =
                        Hcol[g] + hs[g + (g >> 5)] - P / S;
                }
                float di = dotb[t * 4 + 0] + X_iou[(size_t)st * 3072 + g];
                float doo = dotb[t * 4 + 1] + X_iou[(size_t)st * 3072 + 1024 + g];
                float du = dotb[t * 4 + 2] + X_iou[(size_t)st * 3072 + 2048 + g];
                float df = dotb[t * 4 + 3] + X_f[(size_t)st * 1024 + g];
                float ig = sigm(di), og = sigm(doo), fg = sigm(df);
                float ug = fast_tanh(du);
                creg = ig * ug + fg * creg;
                gstore(h_new + g, og * fast_tanh(creg));
            }
        }
        gsync(bar, ++ep);

        // ---- Phase B: att_v = h_new @ W_attnh_top (4 rows per block) ----
        {
            float* hn = smem;
            hn[t] = gload(h_new + t);
            hn[t + 512] = gload(h_new + t + 512);
            __syncthreads();
            const int tr = t >> 7, li = t & 127;
            int j = x * 128 + y * 4 + tr;
            const float* wr = WatT + (size_t)j * 1024;
            float4 w0 = *(const float4*)(wr + li * 4);
            float4 w1 = *(const float4*)(wr + 512 + li * 4);
            float4 a0 = *(const float4*)&hn[li * 4];
            float4 a1 = *(const float4*)&hn[512 + li * 4];
            float acc = w0.x * a0.x + w0.y * a0.y + w0.z * a0.z + w0.w * a0.w
                      + w1.x * a1.x + w1.y * a1.y + w1.z * a1.z + w1.w * a1.w;
            acc = wave_red(acc);
            __syncthreads();
            if ((t & 63) == 0) smem[1024 + (t >> 6)] = acc;
            __syncthreads();
            if (t < 4) gstore(att_v + x * 128 + y * 4 + t,
                              smem[1024 + t * 2] + smem[1024 + t * 2 + 1]);
        }
        gsync(bar, ++ep);

        // ---- Phase C: scores -> e (2 rows per block) ----
        {
            float* av = smem;
            av[t] = gload(att_v + t);
            av[t + 512] = gload(att_v + t + 512);
            __syncthreads();
            const int rr = t >> 8, li = t & 255;
            int r = x * 64 + y * 2 + rr;
            int k4 = li * 4;
            float4 hp = *(const float4*)(Hpre + (size_t)r * 1024 + k4);
            float4 a4 = *(const float4*)&av[k4];
            float4 wa = *(const float4*)(Wa + k4);
            float acc = fast_tanh(hp.x + a4.x) * wa.x + fast_tanh(hp.y + a4.y) * wa.y
                      + fast_tanh(hp.z + a4.z) * wa.z + fast_tanh(hp.w + a4.w) * wa.w;
            acc = wave_red(acc);
            __syncthreads();
            if ((t & 63) == 0) smem[1024 + (t >> 6)] = acc;
            __syncthreads();
            if (t < 2) {
                float sc = smem[1024 + t * 4] + smem[1024 + t * 4 + 1]
                         + smem[1024 + t * 4 + 2] + smem[1024 + t * 4 + 3];
                gstore(e + x * 64 + y * 2 + t, __expf(sc));
            }
        }
        gsync(bar, ++ep);
    }

    // ---- Epilogue: out[T-1] ----
    {
        float evv = gload(e + t);
        le[t] = evv;
        float sv = wave_red(evv);
        if ((t & 63) == 0) sred[t >> 6] = sv;
        __syncthreads();
        const int kt = t >> 7, rr = t & 127;
        const float* htp = HT + (size_t)(g_col + kt) * 512;
        float pp = 0.f;
#pragma unroll
        for (int i = 0; i < 4; i++) {
            int r = rr + 128 * i;
            pp = fmaf(le[r], htp[r], pp);
        }
        pp = wave_red(pp);
        if ((t & 63) == 0) sred2[t >> 6] = pp;
        __syncthreads();
        if (t < 4) {
            int g = g_col + t;
            float S = sred[0] + sred[1] + sred[2] + sred[3]
                    + sred[4] + sred[5] + sred[6] + sred[7];
            float P = sred2[t * 2] + sred2[t * 2 + 1];
            out[(size_t)(T_STEPS - 1) * 1024 + g] =
                Hcol[g] + gload(h_new + g) - P / S;
        }
    }
}

extern "C" void kernel_launch(void* const* d_in, const int* in_sizes, int n_in,
                              void* d_out, int out_size, void* d_ws, size_t ws_size,
                              hipStream_t stream) {
    const float* inputs  = (const float*)d_in[0];
    const float* hiddn   = (const float*)d_in[1];
    const float* W_ioux  = (const float*)d_in[2];
    const float* b_ioux  = (const float*)d_in[3];
    const float* W_iouh  = (const float*)d_in[4];
    const float* b_iouh  = (const float*)d_in[5];
    const float* W_fx    = (const float*)d_in[6];
    const float* b_fx    = (const float*)d_in[7];
    const float* W_fh    = (const float*)d_in[8];
    const float* b_fh    = (const float*)d_in[9];
    const float* Wa      = (const float*)d_in[10];
    const float* W_attnh = (const float*)d_in[11];
    const float* b_attnh = (const float*)d_in[12];

    float* ws = (float*)d_ws;
    unsigned short* Wgb = (unsigned short*)(ws + OFF_WGB);
    float* WatT  = ws + OFF_WATT;
    float* Hpre  = ws + OFF_HPRE;
    float* X_iou = ws + OFF_XIOU;
    float* X_f   = ws + OFF_XF;
    unsigned short* Gb = (unsigned short*)(ws + OFF_G);
    float* HT    = ws + OFF_HT;
    float* Hcol  = ws + OFF_HCOL;
    float* HcolW = ws + OFF_HCOLW;
    float* h_new = ws + OFF_HNEW;
    float* e     = ws + OFF_E;
    unsigned* bar = (unsigned*)(ws + OFF_BAR);
    float* att_v = ws + OFF_ATTV;
    float* out   = (float*)d_out;

    // zero h_new, e, barrier (contiguous region)
    hipMemsetAsync(ws + OFF_HNEW, 0, (1024 + 512 + 4112) * sizeof(float), stream);

    build_wg<<<dim3(4, 1024), 256, 0, stream>>>(W_iouh, W_fh, Wgb);
    transpose_g<<<dim3(32, 32), dim3(32, 8), 0, stream>>>(W_attnh, WatT, 1024, 1024);
    transpose_g<<<dim3(32, 16), dim3(32, 8), 0, stream>>>(hiddn, HT, 512, 1024);
    gemm_bias<<<dim3(48, 4), 256, 0, stream>>>(inputs, W_ioux, b_ioux, b_iouh, X_iou, 256, 3072, 1024);
    gemm_bias<<<dim3(16, 4), 256, 0, stream>>>(inputs, W_fx, b_fx, b_fh, X_f, 256, 1024, 1024);
    gemm_bias<<<dim3(16, 8), 256, 0, stream>>>(hiddn, W_attnh + 1024 * 1024, b_attnh, nullptr, Hpre, 512, 1024, 1024);
    colsum_k<<<4, 256, 0, stream>>>(hiddn, Hcol);
    hcolw_k<<<16, 256, 0, stream>>>(Hcol, Wgb, HcolW);
    gemm_gi<<<dim3(48, 8), 256, 0, stream>>>(hiddn, W_iouh, Gb, 512, 3072, 1024, 0);
    gemm_gi<<<dim3(16, 8), 256, 0, stream>>>(hiddn, W_fh, Gb, 512, 1024, 1024, 3);

    recurrent<<<NBLK, NTHR, 0, stream>>>(Wgb, WatT, Hpre, HT, Hcol, HcolW, Gb,
                                         X_iou, X_f, Wa, h_new, att_v, e, bar, out);
}

// Round 9
// 3331.423 us; speedup vs baseline: 1.2642x; 1.2642x over previous
//
#include <hip/hip_runtime.h>
#include <hip/hip_bf16.h>

// ---------------- sizes ----------------
#define T_STEPS 256
#define MDIM 1024
#define MROWS 512
#define NBLK 256
#define NTHR 512

// ws float offsets
#define OFF_WGB     0u                      // bf16 [1024][4096] interleaved gates (2M floats)
#define OFF_WATT    2097152u                // fp32 [1024][1024] W_attnh top, transposed
#define OFF_HPRE    3145728u                // fp32 [512][1024]
#define OFF_XIOU    3670016u                // fp32 [256][3072]
#define OFF_XF      4456448u                // fp32 [256][1024]
#define OFF_G       4718592u                // bf16 [512][4096]  G = H @ Wg (1M floats)
#define OFF_HT      5767168u                // fp32 [1024][512]  H transposed
#define OFF_HCOL    6291456u                // fp32 [1024]
#define OFF_HCOLW   6292480u                // fp32 [4096]  Hcol @ Wg
#define OFF_HNEW    6296576u                // fp32 [1024]   (zeroed)
#define OFF_E       6297600u                // fp32 [512]    (zeroed)
#define OFF_BAR     6298112u                // 4608 u32      (zeroed): 8 flag replicas + 256 slots, stride 16
#define OFF_ATTV    6302720u                // fp32 [1024]

__device__ inline float fast_tanh(float v) {
    float x = fminf(fmaxf(v, -15.f), 15.f);
    float z = __expf(2.f * x);
    return (z - 1.f) / (z + 1.f);
}
__device__ inline float sigm(float v) { return 1.f / (1.f + __expf(-v)); }

__device__ inline float wave_red(float v) {
#pragma unroll
    for (int s = 32; s > 0; s >>= 1) v += __shfl_down(v, s, 64);
    return v;
}

__device__ __host__ inline unsigned short f2b(float f) {
    __hip_bfloat16 h = __float2bfloat16(f);
    return *(unsigned short*)&h;
}
__device__ inline float b2f(unsigned short u) {
    union { unsigned i; float f; } v; v.i = ((unsigned)u) << 16; return v.f;
}

// device-scope relaxed atomics: LLC-direct, no L2 invalidate anywhere
__device__ inline float gload(const float* p) {
    return __hip_atomic_load(p, __ATOMIC_RELAXED, __HIP_MEMORY_SCOPE_AGENT);
}
__device__ inline void gstore(float* p, float v) {
    __hip_atomic_store(p, v, __ATOMIC_RELAXED, __HIP_MEMORY_SCOPE_AGENT);
}

// Root-poller barrier (round-7 shape, best measured) + REPLICATED broadcast
// flag (round-9 change). Evidence: R8's RMW chains serialize at the LLC bank
// (5.2 µs/sync) — store-based arrival on independent lines pipelines freely
// (3.95). Remaining constant = ~256 pollers saturating ONE broadcast line's
// bank service rate. Fix: 8 flag replicas on separate 64B lines, written in
// parallel by threads 0..7 of block 0; waiter b polls replica b&7 (~32
// pollers/line, under service rate). All-RELAXED (R7-validated); data stores
// are agent-scope relaxed + s_waitcnt(0) ack => LLC-visible before arrival.
__device__ inline void gsync(unsigned* bar, unsigned ep) {
    __syncthreads();
    __builtin_amdgcn_s_waitcnt(0);
    if (threadIdx.x == 0)
        __hip_atomic_store(&bar[(32 + blockIdx.x) * 16], ep, __ATOMIC_RELAXED,
                           __HIP_MEMORY_SCOPE_AGENT);
    if (blockIdx.x == 0) {
        if (threadIdx.x < NBLK) {
            while (__hip_atomic_load(&bar[(32 + threadIdx.x) * 16], __ATOMIC_RELAXED,
                                     __HIP_MEMORY_SCOPE_AGENT) < ep)
                __builtin_amdgcn_s_sleep(1);
        }
        __syncthreads();
        if (threadIdx.x < 8)
            __hip_atomic_store(&bar[threadIdx.x * 16], ep, __ATOMIC_RELAXED,
                               __HIP_MEMORY_SCOPE_AGENT);
    } else {
        if (threadIdx.x == 0) {
            while (__hip_atomic_load(&bar[(blockIdx.x & 7) * 16], __ATOMIC_RELAXED,
                                     __HIP_MEMORY_SCOPE_AGENT) < ep)
                __builtin_amdgcn_s_sleep(1);
        }
    }
    __asm__ volatile("" ::: "memory");
    __syncthreads();
}

// -------- precompute kernels --------

// Wgb[k][4g+{0,1,2,3}] = bf16{W_iouh[k][g], W_iouh[k][m+g], W_iouh[k][2m+g], W_fh[k][g]}
__global__ void build_wg(const float* __restrict__ Wiouh, const float* __restrict__ Wfh,
                         unsigned short* __restrict__ Wgb) {
    int k = blockIdx.y;
    int g = blockIdx.x * 256 + threadIdx.x;
    unsigned a = f2b(Wiouh[k * 3072 + g]);
    unsigned b = f2b(Wiouh[k * 3072 + 1024 + g]);
    unsigned c = f2b(Wiouh[k * 3072 + 2048 + g]);
    unsigned d = f2b(Wfh[k * 1024 + g]);
    uint2 p; p.x = a | (b << 16); p.y = c | (d << 16);
    *(uint2*)(Wgb + (size_t)k * 4096 + 4 * g) = p;
}

// dst[c*R + r] = src[r*C + c]
__global__ void transpose_g(const float* __restrict__ src, float* __restrict__ dst,
                            int R, int C) {
    __shared__ float tile[32][33];
    int c = blockIdx.x * 32 + threadIdx.x;
    int r0 = blockIdx.y * 32;
    for (int i = threadIdx.y; i < 32; i += 8)
        tile[i][threadIdx.x] = src[(size_t)(r0 + i) * C + c];
    __syncthreads();
    int r = r0 + threadIdx.x;
    int c0 = blockIdx.x * 32;
    for (int i = threadIdx.y; i < 32; i += 8)
        dst[(size_t)(c0 + i) * R + r] = tile[threadIdx.x][i];
}

// C[M,N] = A[M,K] @ B[K,N] + b1 + b2
__global__ __launch_bounds__(256) void gemm_bias(const float* __restrict__ A,
                                                 const float* __restrict__ B,
                                                 const float* __restrict__ b1,
                                                 const float* __restrict__ b2,
                                                 float* __restrict__ C,
                                                 int M, int N, int K) {
    __shared__ float As[16][68];
    __shared__ float Bs[16][68];
    int t = threadIdx.x;
    int m0 = blockIdx.y * 64, n0 = blockIdx.x * 64;
    int tx = t & 15, ty = t >> 4;
    float acc[4][4] = {};
    for (int kk = 0; kk < K; kk += 16) {
        {
            int m = t >> 2, k4 = (t & 3) * 4;
            const float4 a4 = *(const float4*)(A + (size_t)(m0 + m) * K + kk + k4);
            As[k4 + 0][m] = a4.x; As[k4 + 1][m] = a4.y;
            As[k4 + 2][m] = a4.z; As[k4 + 3][m] = a4.w;
            int kb = t >> 4, n = (t & 15) * 4;
            const float4 b4 = *(const float4*)(B + (size_t)(kk + kb) * N + n0 + n);
            *(float4*)&Bs[kb][n] = b4;
        }
        __syncthreads();
#pragma unroll
        for (int k = 0; k < 16; k++) {
            float a[4], b[4];
            *(float4*)a = *(const float4*)&As[k][ty * 4];
            *(float4*)b = *(const float4*)&Bs[k][tx * 4];
#pragma unroll
            for (int i = 0; i < 4; i++)
#pragma unroll
                for (int j = 0; j < 4; j++)
                    acc[i][j] = fmaf(a[i], b[j], acc[i][j]);
        }
        __syncthreads();
    }
#pragma unroll
    for (int i = 0; i < 4; i++) {
        int m = m0 + ty * 4 + i;
#pragma unroll
        for (int j = 0; j < 4; j++) {
            int n = n0 + tx * 4 + j;
            float v = acc[i][j];
            if (b1) v += b1[n];
            if (b2) v += b2[n];
            C[(size_t)m * N + n] = v;
        }
    }
}

// G-gemm: Gb[m][4*(n%1024) + n/1024 + cofs] = bf16( (A@B)[m][n] )
__global__ __launch_bounds__(256) void gemm_gi(const float* __restrict__ A,
                                               const float* __restrict__ B,
                                               unsigned short* __restrict__ Gb,
                                               int M, int N, int K, int cofs) {
    __shared__ float As[16][68];
    __shared__ float Bs[16][68];
    int t = threadIdx.x;
    int m0 = blockIdx.y * 64, n0 = blockIdx.x * 64;
    int tx = t & 15, ty = t >> 4;
    float acc[4][4] = {};
    for (int kk = 0; kk < K; kk += 16) {
        {
            int m = t >> 2, k4 = (t & 3) * 4;
            const float4 a4 = *(const float4*)(A + (size_t)(m0 + m) * K + kk + k4);
            As[k4 + 0][m] = a4.x; As[k4 + 1][m] = a4.y;
            As[k4 + 2][m] = a4.z; As[k4 + 3][m] = a4.w;
            int kb = t >> 4, n = (t & 15) * 4;
            const float4 b4 = *(const float4*)(B + (size_t)(kk + kb) * N + n0 + n);
            *(float4*)&Bs[kb][n] = b4;
        }
        __syncthreads();
#pragma unroll
        for (int k = 0; k < 16; k++) {
            float a[4], b[4];
            *(float4*)a = *(const float4*)&As[k][ty * 4];
            *(float4*)b = *(const float4*)&Bs[k][tx * 4];
#pragma unroll
            for (int i = 0; i < 4; i++)
#pragma unroll
                for (int j = 0; j < 4; j++)
                    acc[i][j] = fmaf(a[i], b[j], acc[i][j]);
        }
        __syncthreads();
    }
#pragma unroll
    for (int i = 0; i < 4; i++) {
        int m = m0 + ty * 4 + i;
#pragma unroll
        for (int j = 0; j < 4; j++) {
            int n = n0 + tx * 4 + j;
            int cp = 4 * (n & 1023) + (n >> 10) + cofs;
            Gb[(size_t)m * 4096 + cp] = f2b(acc[i][j]);
        }
    }
}

__global__ void colsum_k(const float* __restrict__ H, float* __restrict__ out) {
    int k = blockIdx.x * 256 + threadIdx.x;
    float s = 0.f;
#pragma unroll 8
    for (int r = 0; r < MROWS; r++) s += H[(size_t)r * MDIM + k];
    out[k] = s;
}

// HcolW[j] = sum_k Hcol[k] * Wgb[k][j]
__global__ void hcolw_k(const float* __restrict__ Hcol,
                        const unsigned short* __restrict__ Wgb,
                        float* __restrict__ HcolW) {
    int j = blockIdx.x * 256 + threadIdx.x;
    float acc = 0.f;
#pragma unroll 8
    for (int k = 0; k < 1024; k++)
        acc = fmaf(Hcol[k], b2f(Wgb[(size_t)k * 4096 + j]), acc);
    HcolW[j] = acc;
}

// -------- persistent recurrent kernel --------
__global__ __launch_bounds__(NTHR) void recurrent(
    const unsigned short* __restrict__ Wgb, const float* __restrict__ WatT,
    const float* __restrict__ Hpre, const float* __restrict__ HT,
    const float* __restrict__ Hcol, const float* __restrict__ HcolW,
    const unsigned short* __restrict__ Gb, const float* __restrict__ X_iou,
    const float* __restrict__ X_f, const float* __restrict__ Wa,
    float* h_new, float* att_v, float* e, unsigned* bar, float* out) {

    const int b = blockIdx.x, t = threadIdx.x;
    const int x = b & 7, y = b >> 3;          // XCD-contiguous slices
    const int g_col = x * 128 + y * 4;        // block's 4 output columns
    const int j0 = x * 512 + y * 16;          // block's 16 interleaved gate cols
    unsigned ep = 0;
    float creg = 0.f;                          // cell state (threads t<4)
    __shared__ float smem[2624];
    float* hs   = smem;          // 1056 padded h_new(st-1)
    float* le   = smem + 1056;   // 512 e(st-1)
    float* red  = smem + 1568;   // [32][16] h_new-dot partials
    float* red2 = smem + 2080;   // [32][16] G-corr partials
    float* sred = smem + 2592;   // 8  (S partials)
    float* sred2= smem + 2600;   // 8  (P partials)
    float* dotb = smem + 2608;   // 16

    for (int st = 0; st < T_STEPS; st++) {
        // ---- Phase A: gates + h_new + out[st-1] ----
        {
            float evv = gload(e + t);
            le[t] = evv;
            float hv0 = gload(h_new + t), hv1 = gload(h_new + t + 512);
            hs[t + (t >> 5)] = hv0;
            { int k2 = t + 512; hs[k2 + (k2 >> 5)] = hv1; }
            float sv = wave_red(evv);
            if ((t & 63) == 0) sred[t >> 6] = sv;
            __syncthreads();

            const int jt = t & 15, kq = t >> 4;
            // h_new-dot over k
            const unsigned short* wp = Wgb + (size_t)(kq * 32) * 4096 + j0 + jt;
            float acc = 0.f;
#pragma unroll 8
            for (int i = 0; i < 32; i++) {
                int k = kq * 32 + i;
                acc = fmaf(hs[k + (k >> 5)], b2f(wp[(size_t)i * 4096]), acc);
            }
            red[kq * 16 + jt] = acc;
            // G-correction over r
            const unsigned short* gp = Gb + (size_t)(kq * 16) * 4096 + j0 + jt;
            float acc2 = 0.f;
#pragma unroll 8
            for (int i = 0; i < 16; i++)
                acc2 = fmaf(le[kq * 16 + i], b2f(gp[(size_t)i * 4096]), acc2);
            red2[kq * 16 + jt] = acc2;
            // P for block's 4 out-cols
            {
                const int kt = t >> 7, rr = t & 127;
                const float* htp = HT + (size_t)(g_col + kt) * 512;
                float pp = 0.f;
#pragma unroll
                for (int i = 0; i < 4; i++) {
                    int r = rr + 128 * i;
                    pp = fmaf(le[r], htp[r], pp);
                }
                pp = wave_red(pp);
                if ((t & 63) == 0) sred2[t >> 6] = pp;
            }
            __syncthreads();
            if (t < 16) {
                float s1 = 0.f, s2 = 0.f;
#pragma unroll
                for (int q = 0; q < 32; q++) { s1 += red[q * 16 + t]; s2 += red2[q * 16 + t]; }
                float S = sred[0] + sred[1] + sred[2] + sred[3]
                        + sred[4] + sred[5] + sred[6] + sred[7];
                float invS = (st == 0) ? 0.f : 1.f / S;
                float hw = (st == 0) ? 0.f : HcolW[j0 + t];
                dotb[t] = s1 + hw - invS * s2;
            }
            __syncthreads();
            if (t < 4) {
                int g = g_col + t;
                float S = sred[0] + sred[1] + sred[2] + sred[3]
                        + sred[4] + sred[5] + sred[6] + sred[7];
                if (st > 0) {
                    float P = sred2[t * 2] + sred2[t * 2 + 1];
                    out[(size_t)(st - 1) * 1024 + g] =
                        Hcol[g] + hs[g + (g >> 5)] - P / S;
                }
                float di = dotb[t * 4 + 0] + X_iou[(size_t)st * 3072 + g];
                float doo = dotb[t * 4 + 1] + X_iou[(size_t)st * 3072 + 1024 + g];
                float du = dotb[t * 4 + 2] + X_iou[(size_t)st * 3072 + 2048 + g];
                float df = dotb[t * 4 + 3] + X_f[(size_t)st * 1024 + g];
                float ig = sigm(di), og = sigm(doo), fg = sigm(df);
                float ug = fast_tanh(du);
                creg = ig * ug + fg * creg;
                gstore(h_new + g, og * fast_tanh(creg));
            }
        }
        gsync(bar, ++ep);

        // ---- Phase B: att_v = h_new @ W_attnh_top (4 rows per block) ----
        {
            float* hn = smem;
            hn[t] = gload(h_new + t);
            hn[t + 512] = gload(h_new + t + 512);
            __syncthreads();
            const int tr = t >> 7, li = t & 127;
            int j = x * 128 + y * 4 + tr;
            const float* wr = WatT + (size_t)j * 1024;
            float4 w0 = *(const float4*)(wr + li * 4);
            float4 w1 = *(const float4*)(wr + 512 + li * 4);
            float4 a0 = *(const float4*)&hn[li * 4];
            float4 a1 = *(const float4*)&hn[512 + li * 4];
            float acc = w0.x * a0.x + w0.y * a0.y + w0.z * a0.z + w0.w * a0.w
                      + w1.x * a1.x + w1.y * a1.y + w1.z * a1.z + w1.w * a1.w;
            acc = wave_red(acc);
            __syncthreads();
            if ((t & 63) == 0) smem[1024 + (t >> 6)] = acc;
            __syncthreads();
            if (t < 4) gstore(att_v + x * 128 + y * 4 + t,
                              smem[1024 + t * 2] + smem[1024 + t * 2 + 1]);
        }
        gsync(bar, ++ep);

        // ---- Phase C: scores -> e (2 rows per block) ----
        {
            float* av = smem;
            av[t] = gload(att_v + t);
            av[t + 512] = gload(att_v + t + 512);
            __syncthreads();
            const int rr = t >> 8, li = t & 255;
            int r = x * 64 + y * 2 + rr;
            int k4 = li * 4;
            float4 hp = *(const float4*)(Hpre + (size_t)r * 1024 + k4);
            float4 a4 = *(const float4*)&av[k4];
            float4 wa = *(const float4*)(Wa + k4);
            float acc = fast_tanh(hp.x + a4.x) * wa.x + fast_tanh(hp.y + a4.y) * wa.y
                      + fast_tanh(hp.z + a4.z) * wa.z + fast_tanh(hp.w + a4.w) * wa.w;
            acc = wave_red(acc);
            __syncthreads();
            if ((t & 63) == 0) smem[1024 + (t >> 6)] = acc;
            __syncthreads();
            if (t < 2) {
                float sc = smem[1024 + t * 4] + smem[1024 + t * 4 + 1]
                         + smem[1024 + t * 4 + 2] + smem[1024 + t * 4 + 3];
                gstore(e + x * 64 + y * 2 + t, __expf(sc));
            }
        }
        gsync(bar, ++ep);
    }

    // ---- Epilogue: out[T-1] ----
    {
        float evv = gload(e + t);
        le[t] = evv;
        float sv = wave_red(evv);
        if ((t & 63) == 0) sred[t >> 6] = sv;
        __syncthreads();
        const int kt = t >> 7, rr = t & 127;
        const float* htp = HT + (size_t)(g_col + kt) * 512;
        float pp = 0.f;
#pragma unroll
        for (int i = 0; i < 4; i++) {
            int r = rr + 128 * i;
            pp = fmaf(le[r], htp[r], pp);
        }
        pp = wave_red(pp);
        if ((t & 63) == 0) sred2[t >> 6] = pp;
        __syncthreads();
        if (t < 4) {
            int g = g_col + t;
            float S = sred[0] + sred[1] + sred[2] + sred[3]
                    + sred[4] + sred[5] + sred[6] + sred[7];
            float P = sred2[t * 2] + sred2[t * 2 + 1];
            out[(size_t)(T_STEPS - 1) * 1024 + g] =
                Hcol[g] + gload(h_new + g) - P / S;
        }
    }
}

extern "C" void kernel_launch(void* const* d_in, const int* in_sizes, int n_in,
                              void* d_out, int out_size, void* d_ws, size_t ws_size,
                              hipStream_t stream) {
    const float* inputs  = (const float*)d_in[0];
    const float* hiddn   = (const float*)d_in[1];
    const float* W_ioux  = (const float*)d_in[2];
    const float* b_ioux  = (const float*)d_in[3];
    const float* W_iouh  = (const float*)d_in[4];
    const float* b_iouh  = (const float*)d_in[5];
    const float* W_fx    = (const float*)d_in[6];
    const float* b_fx    = (const float*)d_in[7];
    const float* W_fh    = (const float*)d_in[8];
    const float* b_fh    = (const float*)d_in[9];
    const float* Wa      = (const float*)d_in[10];
    const float* W_attnh = (const float*)d_in[11];
    const float* b_attnh = (const float*)d_in[12];

    float* ws = (float*)d_ws;
    unsigned short* Wgb = (unsigned short*)(ws + OFF_WGB);
    float* WatT  = ws + OFF_WATT;
    float* Hpre  = ws + OFF_HPRE;
    float* X_iou = ws + OFF_XIOU;
    float* X_f   = ws + OFF_XF;
    unsigned short* Gb = (unsigned short*)(ws + OFF_G);
    float* HT    = ws + OFF_HT;
    float* Hcol  = ws + OFF_HCOL;
    float* HcolW = ws + OFF_HCOLW;
    float* h_new = ws + OFF_HNEW;
    float* e     = ws + OFF_E;
    unsigned* bar = (unsigned*)(ws + OFF_BAR);
    float* att_v = ws + OFF_ATTV;
    float* out   = (float*)d_out;

    // zero h_new, e, barrier (contiguous region)
    hipMemsetAsync(ws + OFF_HNEW, 0, (1024 + 512 + 4608) * sizeof(float), stream);

    build_wg<<<dim3(4, 1024), 256, 0, stream>>>(W_iouh, W_fh, Wgb);
    transpose_g<<<dim3(32, 32), dim3(32, 8), 0, stream>>>(W_attnh, WatT, 1024, 1024);
    transpose_g<<<dim3(32, 16), dim3(32, 8), 0, stream>>>(hiddn, HT, 512, 1024);
    gemm_bias<<<dim3(48, 4), 256, 0, stream>>>(inputs, W_ioux, b_ioux, b_iouh, X_iou, 256, 3072, 1024);
    gemm_bias<<<dim3(16, 4), 256, 0, stream>>>(inputs, W_fx, b_fx, b_fh, X_f, 256, 1024, 1024);
    gemm_bias<<<dim3(16, 8), 256, 0, stream>>>(hiddn, W_attnh + 1024 * 1024, b_attnh, nullptr, Hpre, 512, 1024, 1024);
    colsum_k<<<4, 256, 0, stream>>>(hiddn, Hcol);
    hcolw_k<<<16, 256, 0, stream>>>(Hcol, Wgb, HcolW);
    gemm_gi<<<dim3(48, 8), 256, 0, stream>>>(hiddn, W_iouh, Gb, 512, 3072, 1024, 0);
    gemm_gi<<<dim3(16, 8), 256, 0, stream>>>(hiddn, W_fh, Gb, 512, 1024, 1024, 3);

    recurrent<<<NBLK, NTHR, 0, stream>>>(Wgb, WatT, Hpre, HT, Hcol, HcolW, Gb,
                                         X_iou, X_f, Wa, h_new, att_v, e, bar, out);
}

// Round 10
// 2830.818 us; speedup vs baseline: 1.4877x; 1.1768x over previous
//
#include <hip/hip_runtime.h>
#include <hip/hip_bf16.h>

// ---------------- sizes ----------------
#define T_STEPS 256
#define MDIM 1024
#define MROWS 512
#define NBLK 256
#define NTHR 512

// ws float offsets
#define OFF_WGB     0u                      // bf16 [1024][4096] interleaved gates (2M floats)
#define OFF_WATT    2097152u                // fp32 [1024][1024] W_attnh top, transposed
#define OFF_HPRET   3145728u                // fp32 [1024][512]  Hpre TRANSPOSED
#define OFF_XIOU    3670016u                // fp32 [256][3072]
#define OFF_XF      4456448u                // fp32 [256][1024]
#define OFF_G       4718592u                // bf16 [512][4096]  G = H @ Wg
#define OFF_HT      5767168u                // fp32 [1024][512]  H transposed
#define OFF_HCOL    6291456u                // fp32 [1024]
#define OFF_HCOLW   6292480u                // fp32 [4096]  Hcol @ Wg
#define OFF_HNEW    6296576u                // fp32 [1024]            (zeroed)
#define OFF_SCORE   6297600u                // fp32 [2][8][512] score partial copies (zeroed)
#define OFF_BAR     6305792u                // 4608 u32               (zeroed)

__device__ inline float fast_tanh(float v) {
    float x = fminf(fmaxf(v, -15.f), 15.f);
    float z = __expf(2.f * x);
    return (z - 1.f) / (z + 1.f);
}
__device__ inline float sigm(float v) { return 1.f / (1.f + __expf(-v)); }

__device__ inline float wave_red(float v) {
#pragma unroll
    for (int s = 32; s > 0; s >>= 1) v += __shfl_down(v, s, 64);
    return v;
}

__device__ __host__ inline unsigned short f2b(float f) {
    __hip_bfloat16 h = __float2bfloat16(f);
    return *(unsigned short*)&h;
}
__device__ inline float b2f(unsigned short u) {
    union { unsigned i; float f; } v; v.i = ((unsigned)u) << 16; return v.f;
}

// device-scope relaxed atomics: LLC-direct, no L2 invalidate anywhere
__device__ inline float gload(const float* p) {
    return __hip_atomic_load(p, __ATOMIC_RELAXED, __HIP_MEMORY_SCOPE_AGENT);
}
__device__ inline void gstore(float* p, float v) {
    __hip_atomic_store(p, v, __ATOMIC_RELAXED, __HIP_MEMORY_SCOPE_AGENT);
}
__device__ inline void gatomic_add(float* p, float v) {
    __hip_atomic_fetch_add(p, v, __ATOMIC_RELAXED, __HIP_MEMORY_SCOPE_AGENT);
}

// Round-9 barrier (best measured: 3.84 µs/sync), unchanged this round.
__device__ inline void gsync(unsigned* bar, unsigned ep) {
    __syncthreads();
    __builtin_amdgcn_s_waitcnt(0);
    if (threadIdx.x == 0)
        __hip_atomic_store(&bar[(32 + blockIdx.x) * 16], ep, __ATOMIC_RELAXED,
                           __HIP_MEMORY_SCOPE_AGENT);
    if (blockIdx.x == 0) {
        if (threadIdx.x < NBLK) {
            while (__hip_atomic_load(&bar[(32 + threadIdx.x) * 16], __ATOMIC_RELAXED,
                                     __HIP_MEMORY_SCOPE_AGENT) < ep)
                __builtin_amdgcn_s_sleep(1);
        }
        __syncthreads();
        if (threadIdx.x < 8)
            __hip_atomic_store(&bar[threadIdx.x * 16], ep, __ATOMIC_RELAXED,
                               __HIP_MEMORY_SCOPE_AGENT);
    } else {
        if (threadIdx.x == 0) {
            while (__hip_atomic_load(&bar[(blockIdx.x & 7) * 16], __ATOMIC_RELAXED,
                                     __HIP_MEMORY_SCOPE_AGENT) < ep)
                __builtin_amdgcn_s_sleep(1);
        }
    }
    __asm__ volatile("" ::: "memory");
    __syncthreads();
}

// -------- precompute kernels --------

__global__ void build_wg(const float* __restrict__ Wiouh, const float* __restrict__ Wfh,
                         unsigned short* __restrict__ Wgb) {
    int k = blockIdx.y;
    int g = blockIdx.x * 256 + threadIdx.x;
    unsigned a = f2b(Wiouh[k * 3072 + g]);
    unsigned b = f2b(Wiouh[k * 3072 + 1024 + g]);
    unsigned c = f2b(Wiouh[k * 3072 + 2048 + g]);
    unsigned d = f2b(Wfh[k * 1024 + g]);
    uint2 p; p.x = a | (b << 16); p.y = c | (d << 16);
    *(uint2*)(Wgb + (size_t)k * 4096 + 4 * g) = p;
}

// dst[c*R + r] = src[r*C + c]
__global__ void transpose_g(const float* __restrict__ src, float* __restrict__ dst,
                            int R, int C) {
    __shared__ float tile[32][33];
    int c = blockIdx.x * 32 + threadIdx.x;
    int r0 = blockIdx.y * 32;
    for (int i = threadIdx.y; i < 32; i += 8)
        tile[i][threadIdx.x] = src[(size_t)(r0 + i) * C + c];
    __syncthreads();
    int r = r0 + threadIdx.x;
    int c0 = blockIdx.x * 32;
    for (int i = threadIdx.y; i < 32; i += 8)
        dst[(size_t)(c0 + i) * R + r] = tile[threadIdx.x][i];
}

// C[M,N] = A[M,K] @ B[K,N] + b1 + b2 ; optional transposed store (CT[n*M+m])
__global__ __launch_bounds__(256) void gemm_bias(const float* __restrict__ A,
                                                 const float* __restrict__ B,
                                                 const float* __restrict__ b1,
                                                 const float* __restrict__ b2,
                                                 float* __restrict__ C,
                                                 int M, int N, int K, int tr) {
    __shared__ float As[16][68];
    __shared__ float Bs[16][68];
    int t = threadIdx.x;
    int m0 = blockIdx.y * 64, n0 = blockIdx.x * 64;
    int tx = t & 15, ty = t >> 4;
    float acc[4][4] = {};
    for (int kk = 0; kk < K; kk += 16) {
        {
            int m = t >> 2, k4 = (t & 3) * 4;
            const float4 a4 = *(const float4*)(A + (size_t)(m0 + m) * K + kk + k4);
            As[k4 + 0][m] = a4.x; As[k4 + 1][m] = a4.y;
            As[k4 + 2][m] = a4.z; As[k4 + 3][m] = a4.w;
            int kb = t >> 4, n = (t & 15) * 4;
            const float4 b4 = *(const float4*)(B + (size_t)(kk + kb) * N + n0 + n);
            *(float4*)&Bs[kb][n] = b4;
        }
        __syncthreads();
#pragma unroll
        for (int k = 0; k < 16; k++) {
            float a[4], b[4];
            *(float4*)a = *(const float4*)&As[k][ty * 4];
            *(float4*)b = *(const float4*)&Bs[k][tx * 4];
#pragma unroll
            for (int i = 0; i < 4; i++)
#pragma unroll
                for (int j = 0; j < 4; j++)
                    acc[i][j] = fmaf(a[i], b[j], acc[i][j]);
        }
        __syncthreads();
    }
#pragma unroll
    for (int i = 0; i < 4; i++) {
        int m = m0 + ty * 4 + i;
#pragma unroll
        for (int j = 0; j < 4; j++) {
            int n = n0 + tx * 4 + j;
            float v = acc[i][j];
            if (b1) v += b1[n];
            if (b2) v += b2[n];
            if (tr) C[(size_t)n * M + m] = v;
            else    C[(size_t)m * N + n] = v;
        }
    }
}

// G-gemm: Gb[m][4*(n%1024) + n/1024 + cofs] = bf16( (A@B)[m][n] )
__global__ __launch_bounds__(256) void gemm_gi(const float* __restrict__ A,
                                               const float* __restrict__ B,
                                               unsigned short* __restrict__ Gb,
                                               int M, int N, int K, int cofs) {
    __shared__ float As[16][68];
    __shared__ float Bs[16][68];
    int t = threadIdx.x;
    int m0 = blockIdx.y * 64, n0 = blockIdx.x * 64;
    int tx = t & 15, ty = t >> 4;
    float acc[4][4] = {};
    for (int kk = 0; kk < K; kk += 16) {
        {
            int m = t >> 2, k4 = (t & 3) * 4;
            const float4 a4 = *(const float4*)(A + (size_t)(m0 + m) * K + kk + k4);
            As[k4 + 0][m] = a4.x; As[k4 + 1][m] = a4.y;
            As[k4 + 2][m] = a4.z; As[k4 + 3][m] = a4.w;
            int kb = t >> 4, n = (t & 15) * 4;
            const float4 b4 = *(const float4*)(B + (size_t)(kk + kb) * N + n0 + n);
            *(float4*)&Bs[kb][n] = b4;
        }
        __syncthreads();
#pragma unroll
        for (int k = 0; k < 16; k++) {
            float a[4], b[4];
            *(float4*)a = *(const float4*)&As[k][ty * 4];
            *(float4*)b = *(const float4*)&Bs[k][tx * 4];
#pragma unroll
            for (int i = 0; i < 4; i++)
#pragma unroll
                for (int j = 0; j < 4; j++)
                    acc[i][j] = fmaf(a[i], b[j], acc[i][j]);
        }
        __syncthreads();
    }
#pragma unroll
    for (int i = 0; i < 4; i++) {
        int m = m0 + ty * 4 + i;
#pragma unroll
        for (int j = 0; j < 4; j++) {
            int n = n0 + tx * 4 + j;
            int cp = 4 * (n & 1023) + (n >> 10) + cofs;
            Gb[(size_t)m * 4096 + cp] = f2b(acc[i][j]);
        }
    }
}

__global__ void colsum_k(const float* __restrict__ H, float* __restrict__ out) {
    int k = blockIdx.x * 256 + threadIdx.x;
    float s = 0.f;
#pragma unroll 8
    for (int r = 0; r < MROWS; r++) s += H[(size_t)r * MDIM + k];
    out[k] = s;
}

// HcolW[j] = sum_k Hcol[k] * Wgb[k][j]
__global__ void hcolw_k(const float* __restrict__ Hcol,
                        const unsigned short* __restrict__ Wgb,
                        float* __restrict__ HcolW) {
    int j = blockIdx.x * 256 + threadIdx.x;
    float acc = 0.f;
#pragma unroll 8
    for (int k = 0; k < 1024; k++)
        acc = fmaf(Hcol[k], b2f(Wgb[(size_t)k * 4096 + j]), acc);
    HcolW[j] = acc;
}

// -------- persistent recurrent kernel: 2 syncs/step --------
__global__ __launch_bounds__(NTHR) void recurrent(
    const unsigned short* __restrict__ Wgb, const float* __restrict__ WatT,
    const float* __restrict__ HpreT, const float* __restrict__ HT,
    const float* __restrict__ Hcol, const float* __restrict__ HcolW,
    const unsigned short* __restrict__ Gb, const float* __restrict__ X_iou,
    const float* __restrict__ X_f, const float* __restrict__ Wa,
    float* h_new, float* score, unsigned* bar, float* out) {

    const int b = blockIdx.x, t = threadIdx.x;
    const int x = b & 7, y = b >> 3;          // XCD-contiguous slices
    const int g_col = x * 128 + y * 4;        // block's 4 output/attention columns
    const int j0 = x * 512 + y * 16;          // block's 16 interleaved gate cols
    unsigned ep = 0;
    float creg = 0.f;                          // cell state (threads t<4)
    __shared__ float smem[2624];
    float* hs   = smem;          // 1056 padded h_new(st-1)
    float* le   = smem + 1056;   // 512 e(st-1)
    float* red  = smem + 1568;   // [32][16] h_new-dot partials
    float* red2 = smem + 2080;   // [32][16] G-corr partials
    float* sred = smem + 2592;   // 8  (S partials)
    float* sred2= smem + 2600;   // 8  (P partials)
    float* dotb = smem + 2608;   // 16

    // static per-block attention constants (hoisted)
    const float wa0 = Wa[g_col + 0], wa1 = Wa[g_col + 1];
    const float wa2 = Wa[g_col + 2], wa3 = Wa[g_col + 3];
    const float* hp0 = HpreT + (size_t)(g_col + 0) * 512;
    const float* hp1 = HpreT + (size_t)(g_col + 1) * 512;
    const float* hp2 = HpreT + (size_t)(g_col + 2) * 512;
    const float* hp3 = HpreT + (size_t)(g_col + 3) * 512;

    for (int st = 0; st < T_STEPS; st++) {
        // ---- P1: e (redundant from score copies) + gates + h_new + out[st-1] ----
        {
            const float* sb = score + ((st + 1) & 1) * 4096;   // prev buf
            float sc = 0.f;
#pragma unroll
            for (int c = 0; c < 8; c++) sc += gload(sb + c * 512 + t);
            float evv = __expf(sc);
            le[t] = evv;
            float hv0 = gload(h_new + t), hv1 = gload(h_new + t + 512);
            hs[t + (t >> 5)] = hv0;
            { int k2 = t + 512; hs[k2 + (k2 >> 5)] = hv1; }
            float sv = wave_red(evv);
            if ((t & 63) == 0) sred[t >> 6] = sv;
            __syncthreads();

            const int jt = t & 15, kq = t >> 4;
            // h_new-dot over k
            const unsigned short* wp = Wgb + (size_t)(kq * 32) * 4096 + j0 + jt;
            float acc = 0.f;
#pragma unroll 8
            for (int i = 0; i < 32; i++) {
                int k = kq * 32 + i;
                acc = fmaf(hs[k + (k >> 5)], b2f(wp[(size_t)i * 4096]), acc);
            }
            red[kq * 16 + jt] = acc;
            // G-correction over r
            const unsigned short* gp = Gb + (size_t)(kq * 16) * 4096 + j0 + jt;
            float acc2 = 0.f;
#pragma unroll 8
            for (int i = 0; i < 16; i++)
                acc2 = fmaf(le[kq * 16 + i], b2f(gp[(size_t)i * 4096]), acc2);
            red2[kq * 16 + jt] = acc2;
            // P for block's 4 out-cols
            {
                const int kt = t >> 7, rr = t & 127;
                const float* htp = HT + (size_t)(g_col + kt) * 512;
                float pp = 0.f;
#pragma unroll
                for (int i = 0; i < 4; i++) {
                    int r = rr + 128 * i;
                    pp = fmaf(le[r], htp[r], pp);
                }
                pp = wave_red(pp);
                if ((t & 63) == 0) sred2[t >> 6] = pp;
            }
            __syncthreads();
            if (t < 16) {
                float s1 = 0.f, s2 = 0.f;
#pragma unroll
                for (int q = 0; q < 32; q++) { s1 += red[q * 16 + t]; s2 += red2[q * 16 + t]; }
                float S = sred[0] + sred[1] + sred[2] + sred[3]
                        + sred[4] + sred[5] + sred[6] + sred[7];
                float invS = (st == 0) ? 0.f : 1.f / S;
                float hw = (st == 0) ? 0.f : HcolW[j0 + t];
                dotb[t] = s1 + hw - invS * s2;
            }
            __syncthreads();
            if (t < 4) {
                int g = g_col + t;
                float S = sred[0] + sred[1] + sred[2] + sred[3]
                        + sred[4] + sred[5] + sred[6] + sred[7];
                if (st > 0) {
                    float P = sred2[t * 2] + sred2[t * 2 + 1];
                    out[(size_t)(st - 1) * 1024 + g] =
                        Hcol[g] + hs[g + (g >> 5)] - P / S;
                }
                float di = dotb[t * 4 + 0] + X_iou[(size_t)st * 3072 + g];
                float doo = dotb[t * 4 + 1] + X_iou[(size_t)st * 3072 + 1024 + g];
                float du = dotb[t * 4 + 2] + X_iou[(size_t)st * 3072 + 2048 + g];
                float df = dotb[t * 4 + 3] + X_f[(size_t)st * 1024 + g];
                float ig = sigm(di), og = sigm(doo), fg = sigm(df);
                float ug = fast_tanh(du);
                creg = ig * ug + fg * creg;
                gstore(h_new + g, og * fast_tanh(creg));
            }
        }
        gsync(bar, ++ep);

        // ---- P2: att_v (4 cols) + partial scores for all 512 rows + scatter ----
        {
            float* hn = smem;
            hn[t] = gload(h_new + t);
            hn[t + 512] = gload(h_new + t + 512);
            __syncthreads();
            const int tr = t >> 7, li = t & 127;
            int j = g_col + tr;
            const float* wr = WatT + (size_t)j * 1024;
            float4 w0 = *(const float4*)(wr + li * 4);
            float4 w1 = *(const float4*)(wr + 512 + li * 4);
            float4 a0 = *(const float4*)&hn[li * 4];
            float4 a1 = *(const float4*)&hn[512 + li * 4];
            float acc = w0.x * a0.x + w0.y * a0.y + w0.z * a0.z + w0.w * a0.w
                      + w1.x * a1.x + w1.y * a1.y + w1.z * a1.z + w1.w * a1.w;
            acc = wave_red(acc);
            __syncthreads();
            if ((t & 63) == 0) smem[1024 + (t >> 6)] = acc;
            __syncthreads();
            float av0 = smem[1024 + 0] + smem[1024 + 1];
            float av1 = smem[1024 + 2] + smem[1024 + 3];
            float av2 = smem[1024 + 4] + smem[1024 + 5];
            float av3 = smem[1024 + 6] + smem[1024 + 7];
            // partial score for row t over this block's 4 attention columns
            float ps = wa0 * fast_tanh(hp0[t] + av0)
                     + wa1 * fast_tanh(hp1[t] + av1)
                     + wa2 * fast_tanh(hp2[t] + av2)
                     + wa3 * fast_tanh(hp3[t] + av3);
            gatomic_add(score + (st & 1) * 4096 + x * 512 + t, ps);
            // zero this block's 16-float slice of the buffer P1 just consumed
            if (t < 16)
                gstore(score + ((st + 1) & 1) * 4096 + (b >> 5) * 512 + (b & 31) * 16 + t, 0.f);
        }
        gsync(bar, ++ep);
    }

    // ---- Epilogue: out[T-1] ----
    {
        const float* sb = score + ((T_STEPS - 1) & 1) * 4096;
        float sc = 0.f;
#pragma unroll
        for (int c = 0; c < 8; c++) sc += gload(sb + c * 512 + t);
        float evv = __expf(sc);
        le[t] = evv;
        float sv = wave_red(evv);
        if ((t & 63) == 0) sred[t >> 6] = sv;
        __syncthreads();
        const int kt = t >> 7, rr = t & 127;
        const float* htp = HT + (size_t)(g_col + kt) * 512;
        float pp = 0.f;
#pragma unroll
        for (int i = 0; i < 4; i++) {
            int r = rr + 128 * i;
            pp = fmaf(le[r], htp[r], pp);
        }
        pp = wave_red(pp);
        if ((t & 63) == 0) sred2[t >> 6] = pp;
        __syncthreads();
        if (t < 4) {
            int g = g_col + t;
            float S = sred[0] + sred[1] + sred[2] + sred[3]
                    + sred[4] + sred[5] + sred[6] + sred[7];
            float P = sred2[t * 2] + sred2[t * 2 + 1];
            out[(size_t)(T_STEPS - 1) * 1024 + g] =
                Hcol[g] + gload(h_new + g) - P / S;
        }
    }
}

extern "C" void kernel_launch(void* const* d_in, const int* in_sizes, int n_in,
                              void* d_out, int out_size, void* d_ws, size_t ws_size,
                              hipStream_t stream) {
    const float* inputs  = (const float*)d_in[0];
    const float* hiddn   = (const float*)d_in[1];
    const float* W_ioux  = (const float*)d_in[2];
    const float* b_ioux  = (const float*)d_in[3];
    const float* W_iouh  = (const float*)d_in[4];
    const float* b_iouh  = (const float*)d_in[5];
    const float* W_fx    = (const float*)d_in[6];
    const float* b_fx    = (const float*)d_in[7];
    const float* W_fh    = (const float*)d_in[8];
    const float* b_fh    = (const float*)d_in[9];
    const float* Wa      = (const float*)d_in[10];
    const float* W_attnh = (const float*)d_in[11];
    const float* b_attnh = (const float*)d_in[12];

    float* ws = (float*)d_ws;
    unsigned short* Wgb = (unsigned short*)(ws + OFF_WGB);
    float* WatT  = ws + OFF_WATT;
    float* HpreT = ws + OFF_HPRET;
    float* X_iou = ws + OFF_XIOU;
    float* X_f   = ws + OFF_XF;
    unsigned short* Gb = (unsigned short*)(ws + OFF_G);
    float* HT    = ws + OFF_HT;
    float* Hcol  = ws + OFF_HCOL;
    float* HcolW = ws + OFF_HCOLW;
    float* h_new = ws + OFF_HNEW;
    float* score = ws + OFF_SCORE;
    unsigned* bar = (unsigned*)(ws + OFF_BAR);
    float* out   = (float*)d_out;

    // zero h_new, score buffers, barrier (contiguous region)
    hipMemsetAsync(ws + OFF_HNEW, 0, (1024 + 8192 + 4608) * sizeof(float), stream);

    build_wg<<<dim3(4, 1024), 256, 0, stream>>>(W_iouh, W_fh, Wgb);
    transpose_g<<<dim3(32, 32), dim3(32, 8), 0, stream>>>(W_attnh, WatT, 1024, 1024);
    transpose_g<<<dim3(32, 16), dim3(32, 8), 0, stream>>>(hiddn, HT, 512, 1024);
    gemm_bias<<<dim3(48, 4), 256, 0, stream>>>(inputs, W_ioux, b_ioux, b_iouh, X_iou, 256, 3072, 1024, 0);
    gemm_bias<<<dim3(16, 4), 256, 0, stream>>>(inputs, W_fx, b_fx, b_fh, X_f, 256, 1024, 1024, 0);
    gemm_bias<<<dim3(16, 8), 256, 0, stream>>>(hiddn, W_attnh + 1024 * 1024, b_attnh, nullptr, HpreT, 512, 1024, 1024, 1);
    colsum_k<<<4, 256, 0, stream>>>(hiddn, Hcol);
    hcolw_k<<<16, 256, 0, stream>>>(Hcol, Wgb, HcolW);
    gemm_gi<<<dim3(48, 8), 256, 0, stream>>>(hiddn, W_iouh, Gb, 512, 3072, 1024, 0);
    gemm_gi<<<dim3(16, 8), 256, 0, stream>>>(hiddn, W_fh, Gb, 512, 1024, 1024, 3);

    recurrent<<<NBLK, NTHR, 0, stream>>>(Wgb, WatT, HpreT, HT, Hcol, HcolW, Gb,
                                         X_iou, X_f, Wa, h_new, score, bar, out);
}

// Round 12
// 2482.538 us; speedup vs baseline: 1.6964x; 1.1403x over previous
//
#include <hip/hip_runtime.h>
#include <hip/hip_bf16.h>

// ---------------- sizes ----------------
#define T_STEPS 256
#define MDIM 1024
#define MROWS 512
#define NBLK 256
#define GRID (NBLK + 1)     // +1 dedicated barrier-detector block
#define NTHR 512

// ws float offsets
#define OFF_WGB     0u                      // bf16 [1024][4096] interleaved gates (2M floats)
#define OFF_WATT    2097152u                // fp32 [1024][1024] W_attnh top, transposed
#define OFF_HPRET   3145728u                // fp32 [1024][512]  Hpre TRANSPOSED
#define OFF_XIOU    3670016u                // fp32 [256][3072]
#define OFF_XF      4456448u                // fp32 [256][1024]
#define OFF_G       4718592u                // bf16 [512][4096]  G = H @ Wg
#define OFF_HT      5767168u                // fp32 [1024][512]  H transposed
#define OFF_HCOL    6291456u                // fp32 [1024]
#define OFF_HCOLW   6292480u                // fp32 [4096]  Hcol @ Wg
#define OFF_HNEW    6296576u                // fp32 [1024]            (zeroed)
#define OFF_SCORE   6297600u                // fp32 [2][8][512]       (zeroed)
#define OFF_BAR     6305792u                // 4608 u32               (zeroed)

__device__ inline float fast_tanh(float v) {
    float x = fminf(fmaxf(v, -15.f), 15.f);
    float z = __expf(2.f * x);
    return (z - 1.f) / (z + 1.f);
}
__device__ inline float sigm(float v) { return 1.f / (1.f + __expf(-v)); }

__device__ inline float wave_red(float v) {
#pragma unroll
    for (int s = 32; s > 0; s >>= 1) v += __shfl_down(v, s, 64);
    return v;
}

__device__ __host__ inline unsigned short f2b(float f) {
    __hip_bfloat16 h = __float2bfloat16(f);
    return *(unsigned short*)&h;
}
__device__ inline float b2f(unsigned short u) {
    union { unsigned i; float f; } v; v.i = ((unsigned)u) << 16; return v.f;
}

// device-scope relaxed atomics: LLC-direct, no L2 invalidate anywhere
__device__ inline float gload(const float* p) {
    return __hip_atomic_load(p, __ATOMIC_RELAXED, __HIP_MEMORY_SCOPE_AGENT);
}
__device__ inline void gstore(float* p, float v) {
    __hip_atomic_store(p, v, __ATOMIC_RELAXED, __HIP_MEMORY_SCOPE_AGENT);
}
__device__ inline void gatomic_add(float* p, float v) {
    __hip_atomic_fetch_add(p, v, __ATOMIC_RELAXED, __HIP_MEMORY_SCOPE_AGENT);
}

// Split-phase barrier with DEDICATED detector block.
// R11 deadlock root cause: without a VGPR cap, 512-thr blocks were 1/CU, so
// block 256 (detector) was never resident -> all blocks spun forever.
// R12 fix: __launch_bounds__(512,4) caps VGPR at 128 => >=2 blocks/CU
// capacity => all 257 blocks co-resident by construction.
__device__ inline void barrier_arrive(unsigned* bar, unsigned ep) {
    __syncthreads();
    __builtin_amdgcn_s_waitcnt(0);
    if (threadIdx.x == 0)
        __hip_atomic_store(&bar[(32 + blockIdx.x) * 16], ep, __ATOMIC_RELAXED,
                           __HIP_MEMORY_SCOPE_AGENT);
}
__device__ inline void barrier_wait(unsigned* bar, unsigned ep) {
    if (threadIdx.x == 0) {
        while (__hip_atomic_load(&bar[(blockIdx.x & 7) * 16], __ATOMIC_RELAXED,
                                 __HIP_MEMORY_SCOPE_AGENT) < ep)
            __builtin_amdgcn_s_sleep(1);
    }
    __asm__ volatile("" ::: "memory");
    __syncthreads();
}

// -------- precompute kernels --------

__global__ void build_wg(const float* __restrict__ Wiouh, const float* __restrict__ Wfh,
                         unsigned short* __restrict__ Wgb) {
    int k = blockIdx.y;
    int g = blockIdx.x * 256 + threadIdx.x;
    unsigned a = f2b(Wiouh[k * 3072 + g]);
    unsigned b = f2b(Wiouh[k * 3072 + 1024 + g]);
    unsigned c = f2b(Wiouh[k * 3072 + 2048 + g]);
    unsigned d = f2b(Wfh[k * 1024 + g]);
    uint2 p; p.x = a | (b << 16); p.y = c | (d << 16);
    *(uint2*)(Wgb + (size_t)k * 4096 + 4 * g) = p;
}

// dst[c*R + r] = src[r*C + c]
__global__ void transpose_g(const float* __restrict__ src, float* __restrict__ dst,
                            int R, int C) {
    __shared__ float tile[32][33];
    int c = blockIdx.x * 32 + threadIdx.x;
    int r0 = blockIdx.y * 32;
    for (int i = threadIdx.y; i < 32; i += 8)
        tile[i][threadIdx.x] = src[(size_t)(r0 + i) * C + c];
    __syncthreads();
    int r = r0 + threadIdx.x;
    int c0 = blockIdx.x * 32;
    for (int i = threadIdx.y; i < 32; i += 8)
        dst[(size_t)(c0 + i) * R + r] = tile[threadIdx.x][i];
}

// C[M,N] = A[M,K] @ B[K,N] + b1 + b2 ; optional transposed store (CT[n*M+m])
__global__ __launch_bounds__(256) void gemm_bias(const float* __restrict__ A,
                                                 const float* __restrict__ B,
                                                 const float* __restrict__ b1,
                                                 const float* __restrict__ b2,
                                                 float* __restrict__ C,
                                                 int M, int N, int K, int tr) {
    __shared__ float As[16][68];
    __shared__ float Bs[16][68];
    int t = threadIdx.x;
    int m0 = blockIdx.y * 64, n0 = blockIdx.x * 64;
    int tx = t & 15, ty = t >> 4;
    float acc[4][4] = {};
    for (int kk = 0; kk < K; kk += 16) {
        {
            int m = t >> 2, k4 = (t & 3) * 4;
            const float4 a4 = *(const float4*)(A + (size_t)(m0 + m) * K + kk + k4);
            As[k4 + 0][m] = a4.x; As[k4 + 1][m] = a4.y;
            As[k4 + 2][m] = a4.z; As[k4 + 3][m] = a4.w;
            int kb = t >> 4, n = (t & 15) * 4;
            const float4 b4 = *(const float4*)(B + (size_t)(kk + kb) * N + n0 + n);
            *(float4*)&Bs[kb][n] = b4;
        }
        __syncthreads();
#pragma unroll
        for (int k = 0; k < 16; k++) {
            float a[4], b[4];
            *(float4*)a = *(const float4*)&As[k][ty * 4];
            *(float4*)b = *(const float4*)&Bs[k][tx * 4];
#pragma unroll
            for (int i = 0; i < 4; i++)
#pragma unroll
                for (int j = 0; j < 4; j++)
                    acc[i][j] = fmaf(a[i], b[j], acc[i][j]);
        }
        __syncthreads();
    }
#pragma unroll
    for (int i = 0; i < 4; i++) {
        int m = m0 + ty * 4 + i;
#pragma unroll
        for (int j = 0; j < 4; j++) {
            int n = n0 + tx * 4 + j;
            float v = acc[i][j];
            if (b1) v += b1[n];
            if (b2) v += b2[n];
            if (tr) C[(size_t)n * M + m] = v;
            else    C[(size_t)m * N + n] = v;
        }
    }
}

// G-gemm: Gb[m][4*(n%1024) + n/1024 + cofs] = bf16( (A@B)[m][n] )
__global__ __launch_bounds__(256) void gemm_gi(const float* __restrict__ A,
                                               const float* __restrict__ B,
                                               unsigned short* __restrict__ Gb,
                                               int M, int N, int K, int cofs) {
    __shared__ float As[16][68];
    __shared__ float Bs[16][68];
    int t = threadIdx.x;
    int m0 = blockIdx.y * 64, n0 = blockIdx.x * 64;
    int tx = t & 15, ty = t >> 4;
    float acc[4][4] = {};
    for (int kk = 0; kk < K; kk += 16) {
        {
            int m = t >> 2, k4 = (t & 3) * 4;
            const float4 a4 = *(const float4*)(A + (size_t)(m0 + m) * K + kk + k4);
            As[k4 + 0][m] = a4.x; As[k4 + 1][m] = a4.y;
            As[k4 + 2][m] = a4.z; As[k4 + 3][m] = a4.w;
            int kb = t >> 4, n = (t & 15) * 4;
            const float4 b4 = *(const float4*)(B + (size_t)(kk + kb) * N + n0 + n);
            *(float4*)&Bs[kb][n] = b4;
        }
        __syncthreads();
#pragma unroll
        for (int k = 0; k < 16; k++) {
            float a[4], b[4];
            *(float4*)a = *(const float4*)&As[k][ty * 4];
            *(float4*)b = *(const float4*)&Bs[k][tx * 4];
#pragma unroll
            for (int i = 0; i < 4; i++)
#pragma unroll
                for (int j = 0; j < 4; j++)
                    acc[i][j] = fmaf(a[i], b[j], acc[i][j]);
        }
        __syncthreads();
    }
#pragma unroll
    for (int i = 0; i < 4; i++) {
        int m = m0 + ty * 4 + i;
#pragma unroll
        for (int j = 0; j < 4; j++) {
            int n = n0 + tx * 4 + j;
            int cp = 4 * (n & 1023) + (n >> 10) + cofs;
            Gb[(size_t)m * 4096 + cp] = f2b(acc[i][j]);
        }
    }
}

__global__ void colsum_k(const float* __restrict__ H, float* __restrict__ out) {
    int k = blockIdx.x * 256 + threadIdx.x;
    float s = 0.f;
#pragma unroll 8
    for (int r = 0; r < MROWS; r++) s += H[(size_t)r * MDIM + k];
    out[k] = s;
}

// HcolW[j] = sum_k Hcol[k] * Wgb[k][j]
__global__ void hcolw_k(const float* __restrict__ Hcol,
                        const unsigned short* __restrict__ Wgb,
                        float* __restrict__ HcolW) {
    int j = blockIdx.x * 256 + threadIdx.x;
    float acc = 0.f;
#pragma unroll 8
    for (int k = 0; k < 1024; k++)
        acc = fmaf(Hcol[k], b2f(Wgb[(size_t)k * 4096 + j]), acc);
    HcolW[j] = acc;
}

__device__ inline float sum8(const float* s) {
    return s[0] + s[1] + s[2] + s[3] + s[4] + s[5] + s[6] + s[7];
}

// -------- persistent recurrent kernel: 2 syncs/step, detector + overlap --------
// __launch_bounds__(512,4): VGPR<=128 => >=2 blocks/CU capacity => detector
// block guaranteed resident (R11 deadlock fix).
__global__ __launch_bounds__(NTHR, 4) void recurrent(
    const unsigned short* __restrict__ Wgb, const float* __restrict__ WatT,
    const float* __restrict__ HpreT, const float* __restrict__ HT,
    const float* __restrict__ Hcol, const float* __restrict__ HcolW,
    const unsigned short* __restrict__ Gb, const float* __restrict__ X_iou,
    const float* __restrict__ X_f, const float* __restrict__ Wa,
    float* h_new, float* score, unsigned* bar, float* out) {

    const int b = blockIdx.x, t = threadIdx.x;

    // ---- dedicated detector block ----
    if (b == NBLK) {
        for (unsigned ep = 1; ep <= 2u * T_STEPS; ep++) {
            if (t < NBLK) {
                while (__hip_atomic_load(&bar[(32 + t) * 16], __ATOMIC_RELAXED,
                                         __HIP_MEMORY_SCOPE_AGENT) < ep)
                    __builtin_amdgcn_s_sleep(1);
            }
            __syncthreads();
            if (t < 8)
                __hip_atomic_store(&bar[t * 16], ep, __ATOMIC_RELAXED,
                                   __HIP_MEMORY_SCOPE_AGENT);
            __syncthreads();
        }
        return;
    }

    const int x = b & 7, y = b >> 3;          // XCD-contiguous slices
    const int g_col = x * 128 + y * 4;        // block's 4 output/attention columns
    const int j0 = x * 512 + y * 16;          // block's 16 interleaved gate cols
    unsigned ep = 0;
    float creg = 0.f;                          // cell state (threads t<4)
    __shared__ float smem[2632];
    float* hs   = smem;          // 1056 padded h_new (current)
    float* le   = smem + 1056;   // 512 e
    float* red  = smem + 1568;   // [32][16] s1 partials (written in X overlap)
    float* red2 = smem + 2080;   // [32][16] s2 partials
    float* sred = smem + 2592;   // 8  (S partials)
    float* sred2= smem + 2600;   // 8  (P partials)
    float* dotb = smem + 2608;   // 16
    float* attr = smem + 2624;   // 8  (att_v reduction slots)

    const int jt = t & 15, kq = t >> 4;
    const int li = t & 127, tr = t >> 7;

    // ---- hoist step-invariant loads into registers ----
    float wregf[32];
#pragma unroll
    for (int i = 0; i < 32; i++)
        wregf[i] = b2f(Wgb[(size_t)(kq * 32 + i) * 4096 + j0 + jt]);
    float gregf[16];
#pragma unroll
    for (int i = 0; i < 16; i++)
        gregf[i] = b2f(Gb[(size_t)(kq * 16 + i) * 4096 + j0 + jt]);
    const float* wr = WatT + (size_t)(g_col + tr) * 1024;
    float4 watv0 = *(const float4*)(wr + li * 4);
    float4 watv1 = *(const float4*)(wr + 512 + li * 4);
    float hpr[4], htr[4];
#pragma unroll
    for (int i = 0; i < 4; i++) {
        hpr[i] = HpreT[(size_t)(g_col + i) * 512 + t];
        htr[i] = HT[(size_t)(g_col + tr) * 512 + li + 128 * i];
    }
    const float hcw   = (t < 16) ? HcolW[j0 + t] : 0.f;
    const float hcolg = (t < 4) ? Hcol[g_col + t] : 0.f;
    const float wa0 = Wa[g_col + 0], wa1 = Wa[g_col + 1];
    const float wa2 = Wa[g_col + 2], wa3 = Wa[g_col + 3];

    // ---- prime: stage hs = h_new(=0) and s1 partials for step 0 ----
    hs[t + (t >> 5)] = gload(h_new + t);
    { int k2 = t + 512; hs[k2 + (k2 >> 5)] = gload(h_new + t + 512); }
    __syncthreads();
    {
        float a = 0.f;
#pragma unroll
        for (int i = 0; i < 32; i++) {
            int k = kq * 32 + i;
            a = fmaf(hs[k + (k >> 5)], wregf[i], a);
        }
        red[kq * 16 + jt] = a;
    }

    for (int st = 0; st < T_STEPS; st++) {
        // ---- Y: e (from score copies) + gates + h_new + out[st-1] ----
        {
            float xi0 = 0.f, xi1 = 0.f, xi2 = 0.f, xf0 = 0.f;
            if (t < 4) {                      // prefetch early, consumed at tail
                int g = g_col + t;
                xi0 = X_iou[(size_t)st * 3072 + g];
                xi1 = X_iou[(size_t)st * 3072 + 1024 + g];
                xi2 = X_iou[(size_t)st * 3072 + 2048 + g];
                xf0 = X_f[(size_t)st * 1024 + g];
            }
            const float* sb = score + ((st + 1) & 1) * 4096;
            float sc = 0.f;
#pragma unroll
            for (int c = 0; c < 8; c++) sc += gload(sb + c * 512 + t);
            float evv = __expf(sc);
            le[t] = evv;
            float sv = wave_red(evv);
            if ((t & 63) == 0) sred[t >> 6] = sv;
            __syncthreads();
            // s2 (G-correction) from registers
            float a2 = 0.f;
#pragma unroll
            for (int i = 0; i < 16; i++)
                a2 = fmaf(le[kq * 16 + i], gregf[i], a2);
            red2[kq * 16 + jt] = a2;
            // P for block's 4 out-cols
            float pp = 0.f;
#pragma unroll
            for (int i = 0; i < 4; i++)
                pp = fmaf(le[li + 128 * i], htr[i], pp);
            pp = wave_red(pp);
            if ((t & 63) == 0) sred2[t >> 6] = pp;
            __syncthreads();
            if (t < 16) {
                float s1 = 0.f, s2 = 0.f;
#pragma unroll
                for (int q = 0; q < 32; q++) { s1 += red[q * 16 + t]; s2 += red2[q * 16 + t]; }
                float S = sum8(sred);
                float invS = (st == 0) ? 0.f : 1.f / S;
                float hw = (st == 0) ? 0.f : hcw;
                dotb[t] = s1 + hw - invS * s2;
            }
            __syncthreads();
            if (t < 4) {
                int g = g_col + t;
                if (st > 0) {
                    float S = sum8(sred);
                    float P = sred2[t * 2] + sred2[t * 2 + 1];
                    out[(size_t)(st - 1) * 1024 + g] =
                        hcolg + hs[g + (g >> 5)] - P / S;
                }
                float di = dotb[t * 4 + 0] + xi0;
                float doo = dotb[t * 4 + 1] + xi1;
                float du = dotb[t * 4 + 2] + xi2;
                float df = dotb[t * 4 + 3] + xf0;
                float ig = sigm(di), og = sigm(doo), fg = sigm(df);
                float ug = fast_tanh(du);
                creg = ig * ug + fg * creg;
                gstore(h_new + g, og * fast_tanh(creg));
            }
        }
        { unsigned e1 = ++ep; barrier_arrive(bar, e1); barrier_wait(bar, e1); }

        // ---- X: att_v + partial scores + atomics; s1 overlapped under sync ----
        {
            hs[t + (t >> 5)] = gload(h_new + t);
            { int k2 = t + 512; hs[k2 + (k2 >> 5)] = gload(h_new + t + 512); }
            __syncthreads();
            float acc = 0.f;
#pragma unroll
            for (int i = 0; i < 4; i++) {
                int k = li * 4 + i;
                acc = fmaf(((const float*)&watv0)[i], hs[k + (k >> 5)], acc);
                int k2 = 512 + li * 4 + i;
                acc = fmaf(((const float*)&watv1)[i], hs[k2 + (k2 >> 5)], acc);
            }
            acc = wave_red(acc);
            if ((t & 63) == 0) attr[t >> 6] = acc;
            __syncthreads();
            float av0 = attr[0] + attr[1], av1 = attr[2] + attr[3];
            float av2 = attr[4] + attr[5], av3 = attr[6] + attr[7];
            float ps = wa0 * fast_tanh(hpr[0] + av0)
                     + wa1 * fast_tanh(hpr[1] + av1)
                     + wa2 * fast_tanh(hpr[2] + av2)
                     + wa3 * fast_tanh(hpr[3] + av3);
            gatomic_add(score + (st & 1) * 4096 + x * 512 + t, ps);
            // zero the buffer Y just consumed (read again only 2 syncs later)
            if (t < 16)
                gstore(score + ((st + 1) & 1) * 4096 + (b >> 5) * 512 + (b & 31) * 16 + t, 0.f);
        }
        {
            unsigned e2 = ++ep;
            barrier_arrive(bar, e2);
            // overlap: s1 partials for next step's gates (needs only h_new in hs)
            float a = 0.f;
#pragma unroll
            for (int i = 0; i < 32; i++) {
                int k = kq * 32 + i;
                a = fmaf(hs[k + (k >> 5)], wregf[i], a);
            }
            red[kq * 16 + jt] = a;
            barrier_wait(bar, e2);
        }
    }

    // ---- Epilogue: out[T-1] ----
    {
        const float* sb = score + ((T_STEPS - 1) & 1) * 4096;
        float sc = 0.f;
#pragma unroll
        for (int c = 0; c < 8; c++) sc += gload(sb + c * 512 + t);
        float evv = __expf(sc);
        le[t] = evv;
        float sv = wave_red(evv);
        if ((t & 63) == 0) sred[t >> 6] = sv;
        __syncthreads();
        float pp = 0.f;
#pragma unroll
        for (int i = 0; i < 4; i++)
            pp = fmaf(le[li + 128 * i], htr[i], pp);
        pp = wave_red(pp);
        if ((t & 63) == 0) sred2[t >> 6] = pp;
        __syncthreads();
        if (t < 4) {
            int g = g_col + t;
            float S = sum8(sred);
            float P = sred2[t * 2] + sred2[t * 2 + 1];
            out[(size_t)(T_STEPS - 1) * 1024 + g] =
                hcolg + gload(h_new + g) - P / S;
        }
    }
}

extern "C" void kernel_launch(void* const* d_in, const int* in_sizes, int n_in,
                              void* d_out, int out_size, void* d_ws, size_t ws_size,
                              hipStream_t stream) {
    const float* inputs  = (const float*)d_in[0];
    const float* hiddn   = (const float*)d_in[1];
    const float* W_ioux  = (const float*)d_in[2];
    const float* b_ioux  = (const float*)d_in[3];
    const float* W_iouh  = (const float*)d_in[4];
    const float* b_iouh  = (const float*)d_in[5];
    const float* W_fx    = (const float*)d_in[6];
    const float* b_fx    = (const float*)d_in[7];
    const float* W_fh    = (const float*)d_in[8];
    const float* b_fh    = (const float*)d_in[9];
    const float* Wa      = (const float*)d_in[10];
    const float* W_attnh = (const float*)d_in[11];
    const float* b_attnh = (const float*)d_in[12];

    float* ws = (float*)d_ws;
    unsigned short* Wgb = (unsigned short*)(ws + OFF_WGB);
    float* WatT  = ws + OFF_WATT;
    float* HpreT = ws + OFF_HPRET;
    float* X_iou = ws + OFF_XIOU;
    float* X_f   = ws + OFF_XF;
    unsigned short* Gb = (unsigned short*)(ws + OFF_G);
    float* HT    = ws + OFF_HT;
    float* Hcol  = ws + OFF_HCOL;
    float* HcolW = ws + OFF_HCOLW;
    float* h_new = ws + OFF_HNEW;
    float* score = ws + OFF_SCORE;
    unsigned* bar = (unsigned*)(ws + OFF_BAR);
    float* out   = (float*)d_out;

    // zero h_new, score buffers, barrier (contiguous region)
    hipMemsetAsync(ws + OFF_HNEW, 0, (1024 + 8192 + 4608) * sizeof(float), stream);

    build_wg<<<dim3(4, 1024), 256, 0, stream>>>(W_iouh, W_fh, Wgb);
    transpose_g<<<dim3(32, 32), dim3(32, 8), 0, stream>>>(W_attnh, WatT, 1024, 1024);
    transpose_g<<<dim3(32, 16), dim3(32, 8), 0, stream>>>(hiddn, HT, 512, 1024);
    gemm_bias<<<dim3(48, 4), 256, 0, stream>>>(inputs, W_ioux, b_ioux, b_iouh, X_iou, 256, 3072, 1024, 0);
    gemm_bias<<<dim3(16, 4), 256, 0, stream>>>(inputs, W_fx, b_fx, b_fh, X_f, 256, 1024, 1024, 0);
    gemm_bias<<<dim3(16, 8), 256, 0, stream>>>(hiddn, W_attnh + 1024 * 1024, b_attnh, nullptr, HpreT, 512, 1024, 1024, 1);
    colsum_k<<<4, 256, 0, stream>>>(hiddn, Hcol);
    hcolw_k<<<16, 256, 0, stream>>>(Hcol, Wgb, HcolW);
    gemm_gi<<<dim3(48, 8), 256, 0, stream>>>(hiddn, W_iouh, Gb, 512, 3072, 1024, 0);
    gemm_gi<<<dim3(16, 8), 256, 0, stream>>>(hiddn, W_fh, Gb, 512, 1024, 1024, 3);

    recurrent<<<GRID, NTHR, 0, stream>>>(Wgb, WatT, HpreT, HT, Hcol, HcolW, Gb,
                                         X_iou, X_f, Wa, h_new, score, bar, out);
}